// Round 11
// baseline (269.006 us; speedup 1.0000x reference)
//
#include <hip/hip_runtime.h>
#include <hip/hip_bf16.h>

#define BB 4
#define SS 2048
#define DD 1024
#define HH 16
#define MM (BB * SS)   // 8192

typedef __attribute__((ext_vector_type(8))) short bf16x8;
typedef __attribute__((ext_vector_type(4))) float f32x4;

__device__ __forceinline__ unsigned short f2bf(float f) {
  union { float f; unsigned u; } v; v.f = f;
  unsigned r = v.u + 0x7fffu + ((v.u >> 16) & 1u);
  return (unsigned short)(r >> 16);
}

__device__ __forceinline__ void gl2lds16(const void* g, void* l) {
  __builtin_amdgcn_global_load_lds(
      (const __attribute__((address_space(1))) unsigned int*)g,
      (__attribute__((address_space(3))) unsigned int*)l, 16, 0, 0);
}

// fp32 -> bf16 pre-convert: y<4 -> W[y] (1M each), y>=4 -> X chunk (8M total).
// Wq (y==0) pre-scaled by log2e/8 (softmax scale folded into Q at zero cost).
__global__ __launch_bounds__(256)
void convall(const float* __restrict__ X, const float* __restrict__ a,
             const float* __restrict__ b, const float* __restrict__ c,
             const float* __restrict__ d, unsigned short* __restrict__ wall,
             unsigned short* __restrict__ xb) {
  int y = blockIdx.y;
  const float* s; unsigned short* o; float scl = 1.0f;
  if (y < 4) {
    const float* srcs[4] = {a, b, c, d};
    s = srcs[y]; o = wall + (size_t)y * 1048576;
    if (y == 0) scl = 0.180336880f;   // log2e / 8
  } else {
    s = X + (size_t)(y - 4) * 1048576; o = xb + (size_t)(y - 4) * 1048576;
  }
  int i = (blockIdx.x * 256 + threadIdx.x) * 4;
  float4 v = *(const float4*)(s + i);
  ushort4 h4;
  h4.x = f2bf(v.x * scl); h4.y = f2bf(v.y * scl);
  h4.z = f2bf(v.z * scl); h4.w = f2bf(v.w * scl);
  *(ushort4*)(o + i) = h4;
}

// ---------------------------------------------------------------------------
// R11 QKV GEMM: 128x256 tile, 3-buffer LDS pipeline, uniform counted vmcnt(6).
// C[m,n] = sum_k A[m,k]*W[n,k], bf16 in; n<1024 -> Q, n<2048 -> K,
// n>=2048 -> fused sigma-V^T (verified R10): key = f*16+quad*4+r2 ->
// sigma = 16*quad+4*r2+f, lane's 16 values contiguous -> two uint4 stores.
// Grid: 64 x 12 = 768 blocks = EXACTLY 3 rounds of 256 CUs (zero tail; the
// R10 384-block grid idled ~33% in a half-round).  LDS = 3 bufs x
// (A[128][64] 16KB + B[256][64] 32KB) = 144 KB.  8 waves = 2m x 4n,
// wave tile 64x64, acc[4][4] f32x4.
// Pipeline: tile s read at step s (2 phases: k-slice 0,1); tile s+2 staged
// during step s into buf (s+2)%3 (freed after step s-1) -> 4-phase cover.
// FIFO ledger: at phA(s) outstanding = tile s+1's 6 loads -> PWAIT(6)
// completes everything <= tile s, never drains to 0.  Steps 14,15 stage
// clamped garbage (dead buffers) to keep counts uniform.
// T2 swizzle (verified R10): linear LDS dest + inverse-swizzled global
// SOURCE; phys chunk p of row r holds logical chunk p^(r&7); reads XOR.
// ---------------------------------------------------------------------------
__global__ __launch_bounds__(512, 2)
void gemm256(const unsigned short* __restrict__ A16, const unsigned short* __restrict__ Bp,
             unsigned short* __restrict__ Qo, unsigned short* __restrict__ Ko,
             unsigned short* __restrict__ Vt) {
  extern __shared__ unsigned short L[];   // 73728 shorts = 144 KB
  // A bufs: p*8192 (128x64); B bufs: 24576 + p*16384 (256x64), p = 0..2
  const int Lid = blockIdx.x;
  const int wg = (Lid & 7) * 96 + (Lid >> 3);   // 768 = 8 XCD x 96, bijective
  const int mx = wg & 63, ny = wg >> 6;         // 64 m-tiles x 12 n-tiles
  const int m0 = mx * 128, n0g = ny * 256;

  const int tid = threadIdx.x, lane = tid & 63, wv = tid >> 6;
  const int wave_m = wv >> 2, wave_n = wv & 3;
  const int row_in = lane & 15, quad = lane >> 4;

  // staging lane constants (rule #21: linear dest, inverse-swizzled source)
  const int srow = lane >> 3;
  const int sc = ((lane & 7) ^ (lane >> 3)) * 8;
  const unsigned short* gA0 = A16 + (size_t)(m0 + srow) * DD + sc;
  const unsigned short* gB0 = Bp + (size_t)(n0g + srow) * DD + sc;

  const int aoff = (wave_m * 64 + row_in) * 64;
  const int boff = (wave_n * 64 + row_in) * 64;
  const int swz0 = ((quad) ^ (row_in & 7)) * 8;
  const int swz1 = ((4 + quad) ^ (row_in & 7)) * 8;

  f32x4 acc[4][4] = {};

#define SB3(p, kbv)  /* B rows wv*32+{0,8,16} -> 3 loads */                     \
  do {                                                                          \
    const int ld_ = 24576 + (p) * 16384 + (wv * 32) * 64;                       \
    gl2lds16(gB0 + (size_t)(wv * 32 + 0) * DD + (kbv), L + ld_);                \
    gl2lds16(gB0 + (size_t)(wv * 32 + 8) * DD + (kbv), L + ld_ + 512);          \
    gl2lds16(gB0 + (size_t)(wv * 32 + 16) * DD + (kbv), L + ld_ + 1024);        \
  } while (0)
#define SB1A(p, kbv) /* B row wv*32+24 + A rows wv*16+{0,8} -> 3 loads */       \
  do {                                                                          \
    const int ldb_ = 24576 + (p) * 16384 + (wv * 32) * 64;                      \
    gl2lds16(gB0 + (size_t)(wv * 32 + 24) * DD + (kbv), L + ldb_ + 1536);       \
    const int lda_ = (p) * 8192 + (wv * 16) * 64;                               \
    gl2lds16(gA0 + (size_t)(wv * 16 + 0) * DD + (kbv), L + lda_);               \
    gl2lds16(gA0 + (size_t)(wv * 16 + 8) * DD + (kbv), L + lda_ + 512);         \
  } while (0)
#define LDAB(p, swzv)                                                           \
  do {                                                                          \
    _Pragma("unroll") for (int f = 0; f < 4; ++f)                               \
        af[f] = *(const bf16x8*)(L + (p) * 8192 + aoff + (f * 16) * 64 + (swzv)); \
    _Pragma("unroll") for (int nf = 0; nf < 4; ++nf)                            \
        bk[nf] = *(const bf16x8*)(L + 24576 + (p) * 16384 + boff + (nf * 16) * 64 + (swzv)); \
  } while (0)
#define MFMA16()                                                                \
  do {                                                                          \
    __builtin_amdgcn_s_setprio(1);                                              \
    _Pragma("unroll") for (int f = 0; f < 4; ++f)                               \
        _Pragma("unroll") for (int nf = 0; nf < 4; ++nf)                        \
            acc[f][nf] = __builtin_amdgcn_mfma_f32_16x16x32_bf16(               \
                af[f], bk[nf], acc[f][nf], 0, 0, 0);                            \
    __builtin_amdgcn_s_setprio(0);                                              \
  } while (0)
#define PBAR()                                 \
  do {                                         \
    asm volatile("" ::: "memory");             \
    __builtin_amdgcn_s_barrier();              \
    asm volatile("" ::: "memory");             \
  } while (0)
#define PWAIT(n) asm volatile("s_waitcnt vmcnt(" #n ")" ::: "memory")

  // prologue: tiles 0,1 -> bufs 0,1 (12 loads; issue order = steady state)
  SB3(0, 0);  SB1A(0, 0);
  SB3(1, 64); SB1A(1, 64);

  int pr = 0;
  for (int s = 0; s < 16; ++s) {
    const int kb = (s + 2 < 16 ? s + 2 : 15) * 64;  // clamped source; dest dead
    const int pw = (pr == 0) ? 2 : pr - 1;          // (s+2)%3
    bf16x8 af[4], bk[4];
    // phase A: k-slice 0
    PWAIT(6); PBAR();
    LDAB(pr, swz0);
    SB3(pw, kb);
    MFMA16();
    // phase B: k-slice 1
    PBAR();
    LDAB(pr, swz1);
    SB1A(pw, kb);
    MFMA16();
    pr = (pr == 2) ? 0 : pr + 1;
  }
  asm volatile("s_waitcnt vmcnt(0)" ::: "memory");  // drain garbage stages
#undef SB3
#undef SB1A
#undef LDAB
#undef MFMA16
#undef PBAR
#undef PWAIT

  // epilogue: wave tile 64x64 at (m0 + wave_m*64, n0g + wave_n*64)
  const int seg = n0g >> 10;
  if (seg < 2) {
    unsigned short* Cout = (seg == 0) ? Qo : Ko;
    const int n0 = n0g & 1023;
#pragma unroll
    for (int f = 0; f < 4; ++f)
#pragma unroll
      for (int nf = 0; nf < 4; ++nf)
#pragma unroll
        for (int r2 = 0; r2 < 4; ++r2)
          Cout[(size_t)(m0 + wave_m * 64 + f * 16 + quad * 4 + r2) * DD +
               n0 + wave_n * 64 + nf * 16 + row_in] = f2bf(acc[f][nf][r2]);
  } else {
    // sigma-V^T from registers (verified R10): m = key axis, n = d axis.
    const int b = m0 >> 11;
    const int kt = ((m0 & 2047) >> 6) + wave_m;
    const int h = ((n0g - 2048) >> 6) + wave_n;
#pragma unroll
    for (int nf = 0; nf < 4; ++nf) {
      unsigned short v[16];
#pragma unroll
      for (int j = 0; j < 16; ++j)
        v[j] = f2bf(acc[j & 3][nf][j >> 2]);
      unsigned short* dst = Vt + ((size_t)((b * 16 + h) * 64 + nf * 16 + row_in)) * SS +
                            kt * 64 + quad * 16;
      *(uint4*)dst = *(const uint4*)v;
      *(uint4*)(dst + 8) = *(const uint4*)(v + 8);
    }
  }
}

// O-projection GEMM: R5 128x128 2-phase dbuf structure (proven), fp32 out.
__global__ __launch_bounds__(256)
void gemm_o(const unsigned short* __restrict__ A16, const unsigned short* __restrict__ Bp,
            float* __restrict__ Cout) {
  __shared__ unsigned short As[2 * 4096];
  __shared__ unsigned short Bs[2 * 4096];
  const int m0 = blockIdx.x * 128, n0g = blockIdx.y * 128;
  const int tid = threadIdx.x, lane = tid & 63, wave = tid >> 6;
  const int wm = (wave & 1) * 64, wn = (wave >> 1) * 64;
  const int row_in = lane & 15, quad = lane >> 4;

  f32x4 acc[4][4] = {};

  const int r = wave * 32 + (lane >> 2);
  const unsigned short* gB = Bp + (size_t)(n0g + r) * DD + (lane & 3) * 8;
  const unsigned short* gA = A16 + (size_t)(m0 + r) * DD + (lane & 3) * 8;

  gl2lds16(gB, Bs + (wave * 32) * 32);
  gl2lds16(gB + (size_t)16 * DD, Bs + (wave * 32 + 16) * 32);
  gl2lds16(gA, As + (wave * 32) * 32);
  gl2lds16(gA + (size_t)16 * DD, As + (wave * 32 + 16) * 32);

  int cur = 0;
  for (int kb = 0; kb < DD; kb += 32) {
    __syncthreads();
    if (kb + 32 < DD) {
      const int nx = (cur ^ 1) * 4096;
      gl2lds16(gB + kb + 32, Bs + nx + (wave * 32) * 32);
      gl2lds16(gB + kb + 32 + (size_t)16 * DD, Bs + nx + (wave * 32 + 16) * 32);
      gl2lds16(gA + kb + 32, As + nx + (wave * 32) * 32);
      gl2lds16(gA + kb + 32 + (size_t)16 * DD, As + nx + (wave * 32 + 16) * 32);
    }
    const int cb = cur * 4096;
    bf16x8 af[4], bfr[4];
#pragma unroll
    for (int i = 0; i < 4; ++i)
      af[i] = *(const bf16x8*)(As + cb + (wm + i * 16 + row_in) * 32 + quad * 8);
#pragma unroll
    for (int j = 0; j < 4; ++j)
      bfr[j] = *(const bf16x8*)(Bs + cb + (wn + j * 16 + row_in) * 32 + quad * 8);
    __builtin_amdgcn_s_setprio(1);
#pragma unroll
    for (int i = 0; i < 4; ++i)
#pragma unroll
      for (int j = 0; j < 4; ++j)
        acc[i][j] = __builtin_amdgcn_mfma_f32_16x16x32_bf16(af[i], bfr[j], acc[i][j], 0, 0, 0);
    __builtin_amdgcn_s_setprio(0);
    cur ^= 1;
  }
  __syncthreads();

#pragma unroll
  for (int i = 0; i < 4; ++i)
#pragma unroll
    for (int j = 0; j < 4; ++j)
#pragma unroll
      for (int r2 = 0; r2 < 4; ++r2)
        Cout[(size_t)(m0 + wm + i * 16 + quad * 4 + r2) * DD + n0g + wn + j * 16 + row_in] =
            acc[i][j][r2];
}

// Flash attention (R4 shell, proven): 128 q-rows/block, 4 waves x 32 q, 4 blocks/CU;
// XCD remap; reg-prefetch K/V; p = exp2(sacc) (scale folded into Q).
// P->bf16 pack: proven bias-add + v_perm (R9 lesson: RNE cvt_pk changed P
// rounding and failed tolerance — keep round-half-up).
__global__ __launch_bounds__(256, 4)
void attn_kernel(const unsigned short* __restrict__ Q, const unsigned short* __restrict__ K,
                 const unsigned short* __restrict__ Vt_g, unsigned short* __restrict__ AO) {
  __shared__ unsigned short Ks[64 * 72];   // [key][d]
  __shared__ unsigned short Vs[64 * 72];   // [d][sigma(key)]
  __shared__ unsigned short Ps[128 * 72];  // [q perm][sigma(key)]
  const int L = (blockIdx.y << 4) + blockIdx.x;
  const int jj = L >> 3;
  const int qt = jj & 15;
  const int bh = (L & 7) + ((jj >> 4) << 3);
  const int b = bh >> 4, h = bh & 15;
  const int tid = threadIdx.x, lane = tid & 63, w = tid >> 6;
  const int row_in = lane & 15, quad = lane >> 4;
  const size_t qbase = ((size_t)(b * SS + qt * 128)) * DD + h * 64;

  bf16x8 aq[2][2];
#pragma unroll
  for (int m = 0; m < 2; ++m) {
    const unsigned short* qp = Q + qbase + (size_t)(w * 32 + m * 16 + row_in) * DD;
    aq[m][0] = *(const bf16x8*)(qp + quad * 8);
    aq[m][1] = *(const bf16x8*)(qp + 32 + quad * 8);
  }
  f32x4 oacc[2][4] = {};
  float lrow[2][4] = {};
  const int permr = 2 * (row_in >> 2) + (row_in & 1) + 8 * ((row_in >> 1) & 1);
  const int pw_base = (w * 32) * 72;

  const int r0 = tid >> 3, o80 = (tid & 7) * 8;
  const int r1 = (tid + 256) >> 3, o81 = o80;
  const unsigned short* kp0 = K + ((size_t)(b * SS + r0)) * DD + h * 64 + o80;
  const unsigned short* kp1 = K + ((size_t)(b * SS + r1)) * DD + h * 64 + o81;
  const unsigned short* vp0 = Vt_g + ((size_t)(bh * 64 + r0)) * SS + o80;
  const unsigned short* vp1 = Vt_g + ((size_t)(bh * 64 + r1)) * SS + o81;

  uint4 kr0 = *(const uint4*)kp0;
  uint4 kr1 = *(const uint4*)kp1;
  uint4 vr0 = *(const uint4*)vp0;
  uint4 vr1 = *(const uint4*)vp1;

  for (int kt = 0; kt < SS / 64; ++kt) {
    __syncthreads();
    *(uint4*)(Ks + r0 * 72 + o80) = kr0;
    *(uint4*)(Ks + r1 * 72 + o81) = kr1;
    *(uint4*)(Vs + r0 * 72 + o80) = vr0;
    *(uint4*)(Vs + r1 * 72 + o81) = vr1;
    __syncthreads();
    if (kt + 1 < SS / 64) {
      const size_t ko = (size_t)(kt + 1) * 64 * DD;
      const size_t vo = (size_t)(kt + 1) * 64;
      kr0 = *(const uint4*)(kp0 + ko);
      kr1 = *(const uint4*)(kp1 + ko);
      vr0 = *(const uint4*)(vp0 + vo);
      vr1 = *(const uint4*)(vp1 + vo);
    }

    f32x4 sacc[2][4] = {};
    __builtin_amdgcn_s_setprio(1);
#pragma unroll
    for (int n = 0; n < 4; ++n) {
      bf16x8 bk0 = *(const bf16x8*)(Ks + (n * 16 + row_in) * 72 + quad * 8);
      bf16x8 bk1 = *(const bf16x8*)(Ks + (n * 16 + row_in) * 72 + 32 + quad * 8);
#pragma unroll
      for (int m = 0; m < 2; ++m) {
        sacc[m][n] = __builtin_amdgcn_mfma_f32_16x16x32_bf16(aq[m][0], bk0, sacc[m][n], 0, 0, 0);
        sacc[m][n] = __builtin_amdgcn_mfma_f32_16x16x32_bf16(aq[m][1], bk1, sacc[m][n], 0, 0, 0);
      }
    }
    __builtin_amdgcn_s_setprio(0);

#pragma unroll
    for (int m = 0; m < 2; ++m)
#pragma unroll
      for (int r = 0; r < 4; ++r) {
        int prow = pw_base + (m * 16 + 2 * quad + (r & 1) + 8 * ((r >> 1) & 1)) * 72;
        union { float f; unsigned u; } p0, p1, p2, p3;
        p0.f = __builtin_amdgcn_exp2f(sacc[m][0][r]);
        p1.f = __builtin_amdgcn_exp2f(sacc[m][1][r]);
        p2.f = __builtin_amdgcn_exp2f(sacc[m][2][r]);
        p3.f = __builtin_amdgcn_exp2f(sacc[m][3][r]);
        lrow[m][r] += (p0.f + p1.f) + (p2.f + p3.f);
        unsigned w01 = __builtin_amdgcn_perm(p1.u + 0x8000u, p0.u + 0x8000u, 0x07060302);
        unsigned w23 = __builtin_amdgcn_perm(p3.u + 0x8000u, p2.u + 0x8000u, 0x07060302);
        *(uint2*)(Ps + prow + row_in * 4) = make_uint2(w01, w23);
      }

    __builtin_amdgcn_s_setprio(1);
#pragma unroll
    for (int c = 0; c < 2; ++c) {
      bf16x8 ap0 = *(const bf16x8*)(Ps + pw_base + (permr) * 72 + c * 32 + quad * 8);
      bf16x8 ap1 = *(const bf16x8*)(Ps + pw_base + (16 + permr) * 72 + c * 32 + quad * 8);
#pragma unroll
      for (int t = 0; t < 4; ++t) {
        bf16x8 bv = *(const bf16x8*)(Vs + (t * 16 + row_in) * 72 + c * 32 + quad * 8);
        oacc[0][t] = __builtin_amdgcn_mfma_f32_16x16x32_bf16(ap0, bv, oacc[0][t], 0, 0, 0);
        oacc[1][t] = __builtin_amdgcn_mfma_f32_16x16x32_bf16(ap1, bv, oacc[1][t], 0, 0, 0);
      }
    }
    __builtin_amdgcn_s_setprio(0);
  }

#pragma unroll
  for (int m = 0; m < 2; ++m)
#pragma unroll
    for (int r = 0; r < 4; ++r) {
#pragma unroll
      for (int s = 1; s < 16; s <<= 1) lrow[m][r] += __shfl_xor(lrow[m][r], s, 64);
      float inv = 1.0f / lrow[m][r];
#pragma unroll
      for (int t = 0; t < 4; ++t)
        AO[qbase + (size_t)(w * 32 + m * 16 + quad * 4 + r) * DD + t * 16 + row_in] =
            f2bf(oacc[m][t][r] * inv);
    }
}

extern "C" void kernel_launch(void* const* d_in, const int* in_sizes, int n_in,
                              void* d_out, int out_size, void* d_ws, size_t ws_size,
                              hipStream_t stream) {
  const float* X  = (const float*)d_in[0];
  const float* Wq = (const float*)d_in[1];
  const float* Wk = (const float*)d_in[2];
  const float* Wv = (const float*)d_in[3];
  const float* Wo = (const float*)d_in[4];

  unsigned short* ws   = (unsigned short*)d_ws;
  unsigned short* Qb   = ws;                           // 16 MiB — also AO
  unsigned short* Kb   = Qb + (size_t)MM * DD;         // 16 MiB
  unsigned short* Vtb  = Kb + (size_t)MM * DD;         // 16 MiB, [bh][d][sigma(s)]
  unsigned short* Wall = Vtb + (size_t)MM * DD;        // 8 MiB (Wq,Wk,Wv,Wo bf16)
  unsigned short* Xb   = (unsigned short*)d_out;       // 16 MiB scratch (d_out lo)
  float* out = (float*)d_out;

  static int inited = 0;
  if (!inited) {
    (void)hipFuncSetAttribute((const void*)gemm256,
                              hipFuncAttributeMaxDynamicSharedMemorySize, 147456);
    inited = 1;
  }

  convall<<<dim3(1024, 12), 256, 0, stream>>>(X, Wq, Wk, Wv, Wo, Wall, Xb);

  gemm256<<<dim3(768), 512, 147456, stream>>>(Xb, Wall, Qb, Kb, Vtb);

  attn_kernel<<<dim3(SS / 128, BB * HH), 256, 0, stream>>>(Qb, Kb, Vtb, Qb);

  gemm_o<<<dim3(MM / 128, 8), 256, 0, stream>>>(Qb, Wall + (size_t)3 * 1048576, out);
}

// Round 13
// 267.840 us; speedup vs baseline: 1.0044x; 1.0044x over previous
//
#include <hip/hip_runtime.h>
#include <hip/hip_bf16.h>

#define BB 4
#define SS 2048
#define DD 1024
#define HH 16
#define MM (BB * SS)   // 8192

typedef __attribute__((ext_vector_type(8))) short bf16x8;
typedef __attribute__((ext_vector_type(4))) float f32x4;

__device__ __forceinline__ unsigned short f2bf(float f) {
  union { float f; unsigned u; } v; v.f = f;
  unsigned r = v.u + 0x7fffu + ((v.u >> 16) & 1u);
  return (unsigned short)(r >> 16);
}

__device__ __forceinline__ void gl2lds16(const void* g, void* l) {
  __builtin_amdgcn_global_load_lds(
      (const __attribute__((address_space(1))) unsigned int*)g,
      (__attribute__((address_space(3))) unsigned int*)l, 16, 0, 0);
}

// fp32 -> bf16 pre-convert: y<4 -> W[y] (1M each), y>=4 -> X chunk (8M total).
// Wq (y==0) pre-scaled by log2e/8 (softmax scale folded into Q at zero cost).
__global__ __launch_bounds__(256)
void convall(const float* __restrict__ X, const float* __restrict__ a,
             const float* __restrict__ b, const float* __restrict__ c,
             const float* __restrict__ d, unsigned short* __restrict__ wall,
             unsigned short* __restrict__ xb) {
  int y = blockIdx.y;
  const float* s; unsigned short* o; float scl = 1.0f;
  if (y < 4) {
    const float* srcs[4] = {a, b, c, d};
    s = srcs[y]; o = wall + (size_t)y * 1048576;
    if (y == 0) scl = 0.180336880f;   // log2e / 8
  } else {
    s = X + (size_t)(y - 4) * 1048576; o = xb + (size_t)(y - 4) * 1048576;
  }
  int i = (blockIdx.x * 256 + threadIdx.x) * 4;
  float4 v = *(const float4*)(s + i);
  ushort4 h4;
  h4.x = f2bf(v.x * scl); h4.y = f2bf(v.y * scl);
  h4.z = f2bf(v.z * scl); h4.w = f2bf(v.w * scl);
  *(ushort4*)(o + i) = h4;
}

// ---------------------------------------------------------------------------
// QKV GEMM (verified R10): 256x256 8-phase, T2+T3+T4+T5, fused sigma-V^T
// epilogue.  R11/R12 lessons recorded: (a) 128x256 tiling raised staging
// intensity and HBM fetch 384->576 MB — lost to 256^2 for this shape;
// (b) the 3-buffer uniform-vmcnt(6) variant has a marginal staging race
// (R12 fail with ~2e-3 deviations; R11's "pass" was masked by downstream
// bf16+softmax smoothing) — do not reuse without a real race screen.
// ---------------------------------------------------------------------------
__global__ __launch_bounds__(512, 2)
void gemm256(const unsigned short* __restrict__ A16, const unsigned short* __restrict__ Bp,
             unsigned short* __restrict__ Qo, unsigned short* __restrict__ Ko,
             unsigned short* __restrict__ Vt) {
  extern __shared__ unsigned short L[];   // 65536 shorts = 128 KB
  // XCD-bijective remap: 384 blocks = 8 XCD x 48
  const int Lid = blockIdx.x;
  const int wg = (Lid & 7) * 48 + (Lid >> 3);
  const int mx = wg & 31, ny = wg >> 5;
  const int m0 = mx * 256, n0g = ny * 256;

  const int tid = threadIdx.x, lane = tid & 63, wv = tid >> 6;
  const int wave_m = wv >> 2, wave_n = wv & 3;
  const int row_in = lane & 15, quad = lane >> 4;

  const int srow = lane >> 3;
  const int sc = ((lane & 7) ^ (lane >> 3)) * 8;
  const unsigned short* gA0 = A16 + (size_t)(m0 + srow) * DD + sc;
  const unsigned short* gB0 = Bp + (size_t)(n0g + srow) * DD + sc;

  const int aoff = (wave_m * 128 + row_in) * 64;
  const int boff = (wave_n * 64 + row_in) * 64;
  const int swz0 = ((quad) ^ (row_in & 7)) * 8;
  const int swz1 = ((4 + quad) ^ (row_in & 7)) * 8;

  f32x4 acc[8][4] = {};

#define SA(a, par, kbv)                                                         \
  do {                                                                          \
    const int ld_ = (par) * 16384 + (a) * 8192 + (wv * 16) * 64;                \
    gl2lds16(gA0 + (size_t)((a) * 128 + wv * 16 + 0) * DD + (kbv), L + ld_);    \
    gl2lds16(gA0 + (size_t)((a) * 128 + wv * 16 + 8) * DD + (kbv), L + ld_ + 512); \
  } while (0)
#define SBf(par, kbv)                                                           \
  do {                                                                          \
    const int ld_ = 32768 + (par) * 16384 + (wv * 32) * 64;                     \
    gl2lds16(gB0 + (size_t)(wv * 32 + 0) * DD + (kbv), L + ld_);                \
    gl2lds16(gB0 + (size_t)(wv * 32 + 8) * DD + (kbv), L + ld_ + 512);          \
    gl2lds16(gB0 + (size_t)(wv * 32 + 16) * DD + (kbv), L + ld_ + 1024);        \
    gl2lds16(gB0 + (size_t)(wv * 32 + 24) * DD + (kbv), L + ld_ + 1536);        \
  } while (0)
#define LDA(par, mh, swzv)                                                      \
  do {                                                                          \
    _Pragma("unroll") for (int f = 0; f < 4; ++f)                               \
        af[f] = *(const bf16x8*)(L + (par) * 16384 + aoff + ((mh) * 64 + f * 16) * 64 + (swzv)); \
  } while (0)
#define LDB(par, swzv)                                                          \
  do {                                                                          \
    _Pragma("unroll") for (int nf = 0; nf < 4; ++nf)                            \
        bk[nf] = *(const bf16x8*)(L + 32768 + (par) * 16384 + boff + nf * 1024 + (swzv)); \
  } while (0)
#define MFMA16(mh)                                                              \
  do {                                                                          \
    __builtin_amdgcn_s_setprio(1);                                              \
    _Pragma("unroll") for (int f = 0; f < 4; ++f)                               \
        _Pragma("unroll") for (int nf = 0; nf < 4; ++nf)                        \
            acc[(mh) * 4 + f][nf] = __builtin_amdgcn_mfma_f32_16x16x32_bf16(    \
                af[f], bk[nf], acc[(mh) * 4 + f][nf], 0, 0, 0);                 \
    __builtin_amdgcn_s_setprio(0);                                              \
  } while (0)
#define PBAR()                                 \
  do {                                         \
    asm volatile("" ::: "memory");             \
    __builtin_amdgcn_s_barrier();              \
    asm volatile("" ::: "memory");             \
  } while (0)
#define PWAIT(n) asm volatile("s_waitcnt vmcnt(" #n ")" ::: "memory")

  // prologue: [t0.A0, t0.B, t0.A1, t1.A0]
  SA(0, 0, 0);
  SBf(0, 0);
  SA(1, 0, 0);
  SA(0, 1, 64);

  for (int i = 0; i < 8; ++i) {
    const int kb1 = (2 * i + 1) * 64;
    const int t2 = 2 * i + 2, t3 = 2 * i + 3;
    const int kb2 = (t2 < 16 ? t2 : 15) * 64;   // clamped source; dest slot dead
    const int kb3 = (t3 < 16 ? t3 : 15) * 64;
    bf16x8 af[4], bk[4];
    // ph1 (k0,mL buf0)
    PWAIT(4); PBAR();
    LDB(0, swz0); LDA(0, 0, swz0);
    SBf(1, kb1);
    MFMA16(0);
    // ph2 (k0,mU)
    PWAIT(6); PBAR();
    LDA(0, 1, swz0);
    SA(1, 1, kb1);
    MFMA16(1);
    // ph3 (k1,mL)
    PBAR();
    LDB(0, swz1); LDA(0, 0, swz1);
    MFMA16(0);
    // ph4 (k1,mU)
    PBAR();
    LDA(0, 1, swz1);
    SA(0, 0, kb2);
    MFMA16(1);
    // ph5 (k0,mL buf1)
    PWAIT(4); PBAR();
    LDB(1, swz0); LDA(1, 0, swz0);
    SBf(0, kb2);
    MFMA16(0);
    // ph6 (k0,mU)
    PWAIT(6); PBAR();
    LDA(1, 1, swz0);
    SA(1, 0, kb2);
    MFMA16(1);
    // ph7 (k1,mL)
    PBAR();
    LDB(1, swz1); LDA(1, 0, swz1);
    MFMA16(0);
    // ph8 (k1,mU)
    PBAR();
    LDA(1, 1, swz1);
    SA(0, 1, kb3);
    MFMA16(1);
  }
  asm volatile("s_waitcnt vmcnt(0)" ::: "memory");  // drain garbage stages
#undef SA
#undef SBf
#undef LDA
#undef LDB
#undef MFMA16
#undef PBAR
#undef PWAIT

  // epilogue
  const int seg = n0g >> 10;
  if (seg < 2) {
    unsigned short* Cout = (seg == 0) ? Qo : Ko;
    const int n0 = n0g & 1023;
#pragma unroll
    for (int mh = 0; mh < 2; ++mh)
#pragma unroll
      for (int f = 0; f < 4; ++f)
#pragma unroll
        for (int nf = 0; nf < 4; ++nf)
#pragma unroll
          for (int r2 = 0; r2 < 4; ++r2)
            Cout[(size_t)(m0 + wave_m * 128 + mh * 64 + f * 16 + quad * 4 + r2) * DD +
                 n0 + wave_n * 64 + nf * 16 + row_in] = f2bf(acc[mh * 4 + f][nf][r2]);
  } else {
    // sigma-V^T from registers (verified R10): key = f*16+quad*4+r2 ->
    // sigma = 16*quad+4*r2+f, lane's 16 values contiguous.
    const int b = m0 >> 11;
    const int ktb = ((m0 & 2047) >> 6) + wave_m * 2;
    const int h = ((n0g - 2048) >> 6) + wave_n;
#pragma unroll
    for (int mh = 0; mh < 2; ++mh) {
      const int kt = ktb + mh;
#pragma unroll
      for (int nf = 0; nf < 4; ++nf) {
        unsigned short v[16];
#pragma unroll
        for (int j = 0; j < 16; ++j)
          v[j] = f2bf(acc[mh * 4 + (j & 3)][nf][j >> 2]);
        unsigned short* dst = Vt + ((size_t)((b * 16 + h) * 64 + nf * 16 + row_in)) * SS +
                              kt * 64 + quad * 16;
        *(uint4*)dst = *(const uint4*)v;
        *(uint4*)(dst + 8) = *(const uint4*)(v + 8);
      }
    }
  }
}

// O-projection GEMM: R5 128x128 2-phase dbuf structure (proven), fp32 out.
__global__ __launch_bounds__(256)
void gemm_o(const unsigned short* __restrict__ A16, const unsigned short* __restrict__ Bp,
            float* __restrict__ Cout) {
  __shared__ unsigned short As[2 * 4096];
  __shared__ unsigned short Bs[2 * 4096];
  const int m0 = blockIdx.x * 128, n0g = blockIdx.y * 128;
  const int tid = threadIdx.x, lane = tid & 63, wave = tid >> 6;
  const int wm = (wave & 1) * 64, wn = (wave >> 1) * 64;
  const int row_in = lane & 15, quad = lane >> 4;

  f32x4 acc[4][4] = {};

  const int r = wave * 32 + (lane >> 2);
  const unsigned short* gB = Bp + (size_t)(n0g + r) * DD + (lane & 3) * 8;
  const unsigned short* gA = A16 + (size_t)(m0 + r) * DD + (lane & 3) * 8;

  gl2lds16(gB, Bs + (wave * 32) * 32);
  gl2lds16(gB + (size_t)16 * DD, Bs + (wave * 32 + 16) * 32);
  gl2lds16(gA, As + (wave * 32) * 32);
  gl2lds16(gA + (size_t)16 * DD, As + (wave * 32 + 16) * 32);

  int cur = 0;
  for (int kb = 0; kb < DD; kb += 32) {
    __syncthreads();
    if (kb + 32 < DD) {
      const int nx = (cur ^ 1) * 4096;
      gl2lds16(gB + kb + 32, Bs + nx + (wave * 32) * 32);
      gl2lds16(gB + kb + 32 + (size_t)16 * DD, Bs + nx + (wave * 32 + 16) * 32);
      gl2lds16(gA + kb + 32, As + nx + (wave * 32) * 32);
      gl2lds16(gA + kb + 32 + (size_t)16 * DD, As + nx + (wave * 32 + 16) * 32);
    }
    const int cb = cur * 4096;
    bf16x8 af[4], bfr[4];
#pragma unroll
    for (int i = 0; i < 4; ++i)
      af[i] = *(const bf16x8*)(As + cb + (wm + i * 16 + row_in) * 32 + quad * 8);
#pragma unroll
    for (int j = 0; j < 4; ++j)
      bfr[j] = *(const bf16x8*)(Bs + cb + (wn + j * 16 + row_in) * 32 + quad * 8);
    __builtin_amdgcn_s_setprio(1);
#pragma unroll
    for (int i = 0; i < 4; ++i)
#pragma unroll
      for (int j = 0; j < 4; ++j)
        acc[i][j] = __builtin_amdgcn_mfma_f32_16x16x32_bf16(af[i], bfr[j], acc[i][j], 0, 0, 0);
    __builtin_amdgcn_s_setprio(0);
    cur ^= 1;
  }
  __syncthreads();

#pragma unroll
  for (int i = 0; i < 4; ++i)
#pragma unroll
    for (int j = 0; j < 4; ++j)
#pragma unroll
      for (int r2 = 0; r2 < 4; ++r2)
        Cout[(size_t)(m0 + wm + i * 16 + quad * 4 + r2) * DD + n0g + wn + j * 16 + row_in] =
            acc[i][j][r2];
}

// Flash attention (R4 shell, proven): 128 q-rows/block, 4 waves x 32 q, 4 blocks/CU;
// XCD remap; reg-prefetch K/V; p = exp2(sacc) (scale folded into Q).
// P->bf16 pack: proven bias-add + v_perm (R9: RNE cvt_pk failed tolerance).
__global__ __launch_bounds__(256, 4)
void attn_kernel(const unsigned short* __restrict__ Q, const unsigned short* __restrict__ K,
                 const unsigned short* __restrict__ Vt_g, unsigned short* __restrict__ AO) {
  __shared__ unsigned short Ks[64 * 72];   // [key][d]
  __shared__ unsigned short Vs[64 * 72];   // [d][sigma(key)]
  __shared__ unsigned short Ps[128 * 72];  // [q perm][sigma(key)]
  const int L = (blockIdx.y << 4) + blockIdx.x;
  const int jj = L >> 3;
  const int qt = jj & 15;
  const int bh = (L & 7) + ((jj >> 4) << 3);
  const int b = bh >> 4, h = bh & 15;
  const int tid = threadIdx.x, lane = tid & 63, w = tid >> 6;
  const int row_in = lane & 15, quad = lane >> 4;
  const size_t qbase = ((size_t)(b * SS + qt * 128)) * DD + h * 64;

  bf16x8 aq[2][2];
#pragma unroll
  for (int m = 0; m < 2; ++m) {
    const unsigned short* qp = Q + qbase + (size_t)(w * 32 + m * 16 + row_in) * DD;
    aq[m][0] = *(const bf16x8*)(qp + quad * 8);
    aq[m][1] = *(const bf16x8*)(qp + 32 + quad * 8);
  }
  f32x4 oacc[2][4] = {};
  float lrow[2][4] = {};
  const int permr = 2 * (row_in >> 2) + (row_in & 1) + 8 * ((row_in >> 1) & 1);
  const int pw_base = (w * 32) * 72;

  const int r0 = tid >> 3, o80 = (tid & 7) * 8;
  const int r1 = (tid + 256) >> 3, o81 = o80;
  const unsigned short* kp0 = K + ((size_t)(b * SS + r0)) * DD + h * 64 + o80;
  const unsigned short* kp1 = K + ((size_t)(b * SS + r1)) * DD + h * 64 + o81;
  const unsigned short* vp0 = Vt_g + ((size_t)(bh * 64 + r0)) * SS + o80;
  const unsigned short* vp1 = Vt_g + ((size_t)(bh * 64 + r1)) * SS + o81;

  uint4 kr0 = *(const uint4*)kp0;
  uint4 kr1 = *(const uint4*)kp1;
  uint4 vr0 = *(const uint4*)vp0;
  uint4 vr1 = *(const uint4*)vp1;

  for (int kt = 0; kt < SS / 64; ++kt) {
    __syncthreads();
    *(uint4*)(Ks + r0 * 72 + o80) = kr0;
    *(uint4*)(Ks + r1 * 72 + o81) = kr1;
    *(uint4*)(Vs + r0 * 72 + o80) = vr0;
    *(uint4*)(Vs + r1 * 72 + o81) = vr1;
    __syncthreads();
    if (kt + 1 < SS / 64) {
      const size_t ko = (size_t)(kt + 1) * 64 * DD;
      const size_t vo = (size_t)(kt + 1) * 64;
      kr0 = *(const uint4*)(kp0 + ko);
      kr1 = *(const uint4*)(kp1 + ko);
      vr0 = *(const uint4*)(vp0 + vo);
      vr1 = *(const uint4*)(vp1 + vo);
    }

    f32x4 sacc[2][4] = {};
    __builtin_amdgcn_s_setprio(1);
#pragma unroll
    for (int n = 0; n < 4; ++n) {
      bf16x8 bk0 = *(const bf16x8*)(Ks + (n * 16 + row_in) * 72 + quad * 8);
      bf16x8 bk1 = *(const bf16x8*)(Ks + (n * 16 + row_in) * 72 + 32 + quad * 8);
#pragma unroll
      for (int m = 0; m < 2; ++m) {
        sacc[m][n] = __builtin_amdgcn_mfma_f32_16x16x32_bf16(aq[m][0], bk0, sacc[m][n], 0, 0, 0);
        sacc[m][n] = __builtin_amdgcn_mfma_f32_16x16x32_bf16(aq[m][1], bk1, sacc[m][n], 0, 0, 0);
      }
    }
    __builtin_amdgcn_s_setprio(0);

#pragma unroll
    for (int m = 0; m < 2; ++m)
#pragma unroll
      for (int r = 0; r < 4; ++r) {
        int prow = pw_base + (m * 16 + 2 * quad + (r & 1) + 8 * ((r >> 1) & 1)) * 72;
        union { float f; unsigned u; } p0, p1, p2, p3;
        p0.f = __builtin_amdgcn_exp2f(sacc[m][0][r]);
        p1.f = __builtin_amdgcn_exp2f(sacc[m][1][r]);
        p2.f = __builtin_amdgcn_exp2f(sacc[m][2][r]);
        p3.f = __builtin_amdgcn_exp2f(sacc[m][3][r]);
        lrow[m][r] += (p0.f + p1.f) + (p2.f + p3.f);
        unsigned w01 = __builtin_amdgcn_perm(p1.u + 0x8000u, p0.u + 0x8000u, 0x07060302);
        unsigned w23 = __builtin_amdgcn_perm(p3.u + 0x8000u, p2.u + 0x8000u, 0x07060302);
        *(uint2*)(Ps + prow + row_in * 4) = make_uint2(w01, w23);
      }

    __builtin_amdgcn_s_setprio(1);
#pragma unroll
    for (int c = 0; c < 2; ++c) {
      bf16x8 ap0 = *(const bf16x8*)(Ps + pw_base + (permr) * 72 + c * 32 + quad * 8);
      bf16x8 ap1 = *(const bf16x8*)(Ps + pw_base + (16 + permr) * 72 + c * 32 + quad * 8);
#pragma unroll
      for (int t = 0; t < 4; ++t) {
        bf16x8 bv = *(const bf16x8*)(Vs + (t * 16 + row_in) * 72 + c * 32 + quad * 8);
        oacc[0][t] = __builtin_amdgcn_mfma_f32_16x16x32_bf16(ap0, bv, oacc[0][t], 0, 0, 0);
        oacc[1][t] = __builtin_amdgcn_mfma_f32_16x16x32_bf16(ap1, bv, oacc[1][t], 0, 0, 0);
      }
    }
    __builtin_amdgcn_s_setprio(0);
  }

#pragma unroll
  for (int m = 0; m < 2; ++m)
#pragma unroll
    for (int r = 0; r < 4; ++r) {
#pragma unroll
      for (int s = 1; s < 16; s <<= 1) lrow[m][r] += __shfl_xor(lrow[m][r], s, 64);
      float inv = 1.0f / lrow[m][r];
#pragma unroll
      for (int t = 0; t < 4; ++t)
        AO[qbase + (size_t)(w * 32 + m * 16 + quad * 4 + r) * DD + t * 16 + row_in] =
            f2bf(oacc[m][t][r] * inv);
    }
}

extern "C" void kernel_launch(void* const* d_in, const int* in_sizes, int n_in,
                              void* d_out, int out_size, void* d_ws, size_t ws_size,
                              hipStream_t stream) {
  const float* X  = (const float*)d_in[0];
  const float* Wq = (const float*)d_in[1];
  const float* Wk = (const float*)d_in[2];
  const float* Wv = (const float*)d_in[3];
  const float* Wo = (const float*)d_in[4];

  unsigned short* ws   = (unsigned short*)d_ws;
  unsigned short* Qb   = ws;                           // 16 MiB — also AO
  unsigned short* Kb   = Qb + (size_t)MM * DD;         // 16 MiB
  unsigned short* Vtb  = Kb + (size_t)MM * DD;         // 16 MiB, [bh][d][sigma(s)]
  unsigned short* Wall = Vtb + (size_t)MM * DD;        // 8 MiB (Wq,Wk,Wv,Wo bf16)
  unsigned short* Xb   = (unsigned short*)d_out;       // 16 MiB scratch (d_out lo)
  float* out = (float*)d_out;

  static int inited = 0;
  if (!inited) {
    (void)hipFuncSetAttribute((const void*)gemm256,
                              hipFuncAttributeMaxDynamicSharedMemorySize, 131072);
    inited = 1;
  }

  convall<<<dim3(1024, 12), 256, 0, stream>>>(X, Wq, Wk, Wv, Wo, Wall, Xb);

  gemm256<<<dim3(384), 512, 131072, stream>>>(Xb, Wall, Qb, Kb, Vtb);

  attn_kernel<<<dim3(SS / 128, BB * HH), 256, 0, stream>>>(Qb, Kb, Vtb, Qb);

  gemm_o<<<dim3(MM / 128, 8), 256, 0, stream>>>(Qb, Wall + (size_t)3 * 1048576, out);
}